// Round 13
// baseline (795.978 us; speedup 1.0000x reference)
//
#include <hip/hip_runtime.h>
#include <math.h>

typedef unsigned short u16;
typedef __bf16 bf16x8 __attribute__((ext_vector_type(8)));
typedef float f32x4 __attribute__((ext_vector_type(4)));
typedef short s16x8 __attribute__((ext_vector_type(8)));

#define DM 2048
#define NB 4
#define SEQ 2048
#define PAST_N 2048
#define CS 4096

__device__ __forceinline__ u16 f2bf(float f) {
  unsigned u = __float_as_uint(f);
  u += 0x7fff + ((u >> 16) & 1);
  return (u16)(u >> 16);
}
__device__ __forceinline__ float bf2f(u16 h) {
  return __uint_as_float(((unsigned)h) << 16);
}

__device__ __forceinline__ void gl_lds16(const u16* g, u16* l) {
  __builtin_amdgcn_global_load_lds(
      (const __attribute__((address_space(1))) unsigned*)g,
      (__attribute__((address_space(3))) unsigned*)l, 16, 0, 0);
}

// Swizzled LDS fragment read: tile row-major [256 rows][64 k] bf16 (128B/row),
// 16B slots XOR'd by row&7 (r2-verified structure).
__device__ __forceinline__ bf16x8 ldsfrag(const u16* s, int row, int colb) {
  const int byte_off = (row * 128 + colb) ^ ((row & 7) << 4);
  return *(const bf16x8*)((const char*)s + byte_off);
}

// Stage one 256x64 bf16 tile (32KB) with 512 threads: 4 x global_load_lds(16B).
// LDS dest linear (HW); SOURCE column pre-swizzled (rule #21).
__device__ __forceinline__ void stage4(const u16* __restrict__ g, int ld,
                                       u16* lwb, int t) {
#pragma unroll
  for (int j = 0; j < 4; ++j) {
    const int c = j * 512 + t;
    const int row = c >> 3;
    const int slot = (c & 7) ^ (row & 7);
    gl_lds16(g + (long)row * ld + slot * 8, lwb + j * 4096);
  }
}

#define LOADA(mh)                                                       \
  _Pragma("unroll") for (int mi = 0; mi < 4; ++mi) {                    \
    const int rwa = wr * 128 + ((mh) * 4 + mi) * 16 + lr;               \
    a[mi][0] = ldsfrag(sA, rwa, kb0);                                   \
    a[mi][1] = ldsfrag(sA, rwa, 64 + kb0);                              \
  }

#define LOADB_TO(dst, nh)                                               \
  _Pragma("unroll") for (int ni = 0; ni < 2; ++ni) {                    \
    const int rwb = wc * 64 + ((nh) * 2 + ni) * 16 + lr;                \
    dst[ni][0] = ldsfrag(sB, rwb, kb0);                                 \
    dst[ni][1] = ldsfrag(sB, rwb, 64 + kb0);                            \
  }

#define MM(mh, nh, bfr)                                                 \
  _Pragma("unroll") for (int kk = 0; kk < 2; ++kk)                      \
  _Pragma("unroll") for (int mi = 0; mi < 4; ++mi)                      \
  _Pragma("unroll") for (int ni = 0; ni < 2; ++ni)                      \
    acc[(mh) * 4 + mi][(nh) * 2 + ni] =                                 \
        __builtin_amdgcn_mfma_f32_16x16x32_bf16(                        \
            a[mi][kk], bfr[ni][kk], acc[(mh) * 4 + mi][(nh) * 2 + ni],  \
            0, 0, 0);

#define PHASE_SYNC                                                      \
  __builtin_amdgcn_s_barrier();                                         \
  asm volatile("s_waitcnt lgkmcnt(0)" ::: "memory");                    \
  __builtin_amdgcn_sched_barrier(0);

// r2 4-phase K-loop, refined: both next-tile stages at ph0 (3-phase drain
// cover), both B n-halves kept in regs (no ph3 reload), 7 barriers/tile.
#define GEMM_MAIN_LOOP(Abp, Bbp, ldav, ldbv)                            \
  stage4(Abp, ldav, &shA[0][w * 512], t);                               \
  stage4(Bbp, ldbv, &shB[0][w * 512], t);                               \
  asm volatile("s_waitcnt vmcnt(0)" ::: "memory");                      \
  __builtin_amdgcn_s_barrier();                                         \
  for (int tt = 0; tt < NT; ++tt) {                                     \
    const int cur = tt & 1;                                             \
    const u16* sA = shA[cur];                                           \
    const u16* sB = shB[cur];                                           \
    const bool pf = (tt + 1 < NT);                                      \
    const int ko = (tt + 1) << 6;                                       \
    LOADA(0)                                                            \
    LOADB_TO(b0, 0)                                                     \
    if (pf) {                                                           \
      stage4(Abp + ko, ldav, &shA[cur ^ 1][w * 512], t);                \
      stage4(Bbp + ko, ldbv, &shB[cur ^ 1][w * 512], t);                \
    }                                                                   \
    PHASE_SYNC                                                          \
    __builtin_amdgcn_s_setprio(1);                                      \
    MM(0, 0, b0)                                                        \
    __builtin_amdgcn_s_setprio(0);                                      \
    __builtin_amdgcn_s_barrier();                                       \
    LOADB_TO(b1, 1)                                                     \
    PHASE_SYNC                                                          \
    __builtin_amdgcn_s_setprio(1);                                      \
    MM(0, 1, b1)                                                        \
    __builtin_amdgcn_s_setprio(0);                                      \
    __builtin_amdgcn_s_barrier();                                       \
    LOADA(1)                                                            \
    PHASE_SYNC                                                          \
    __builtin_amdgcn_s_setprio(1);                                      \
    MM(1, 1, b1)                                                        \
    __builtin_amdgcn_s_setprio(0);                                      \
    __builtin_amdgcn_s_setprio(1);                                      \
    MM(1, 0, b0)                                                        \
    __builtin_amdgcn_s_setprio(0);                                      \
    if (pf) asm volatile("s_waitcnt vmcnt(0)" ::: "memory");            \
    __builtin_amdgcn_s_barrier();                                       \
  }

// C[M,N] = A[M,K] * B[N,K]^T (r2 core).
// MODE 0: fp32 out (+bias). MODE 1: bf16 out (+bias, *scale).
// MODE 2: scores — write bf16 exp(val); per-row partial sums (this wave's
//         64-col slice) -> part[bz][row][bx*4+wc] fp32.
// MODE 3: PV — preload rowsum partials (64/row), epilogue multiplies 1/sum.
template <int MODE>
__global__ __launch_bounds__(512, 2) void gemm256(
    const u16* __restrict__ A, const u16* __restrict__ B,
    float* __restrict__ Cf, u16* __restrict__ Cb, const float* __restrict__ bias,
    float* __restrict__ part,
    int K, int lda, int ldb, int ldc, long strA, long strB, long strC,
    float scale) {
  __shared__ __align__(16) u16 shA[2][256 * 64];
  __shared__ __align__(16) u16 shB[2][256 * 64];
  __shared__ float ro[256];
  const int t = threadIdx.x;
  const int lane = t & 63;
  const int w = t >> 6;
  const int wr = w >> 2, wc = w & 3;
  const int lr = lane & 15, kb0 = (lane >> 4) * 16;

  const int gx = gridDim.x, gy = gridDim.y;
  const int nwg = gx * gy * gridDim.z;
  const int orig = blockIdx.x + gx * (blockIdx.y + gy * blockIdx.z);
  const int swz = (orig & 7) * (nwg >> 3) + (orig >> 3);
  const int bx = swz % gx;
  const int r1 = swz / gx;
  const int by = r1 % gy;
  const long bz = r1 / gy;
  const int brow = by * 256, bcol = bx * 256;

  const u16* Ab = A + bz * strA + (long)brow * lda;
  const u16* Bb = B + bz * strB + (long)bcol * ldb;
  const int NT = K >> 6;

  if (MODE == 3) {
    if (t < 256) {
      const float* pr = part + (bz * 2048 + brow + t) * 64;
      float s = 0.f;
#pragma unroll 8
      for (int j = 0; j < 64; ++j) s += pr[j];
      ro[t] = 1.0f / s;
    }
    __syncthreads();
  }

  f32x4 acc[8][4] = {};
  bf16x8 a[4][2], b0[2][2], b1[2][2];

  GEMM_MAIN_LOOP(Ab, Bb, lda, ldb)

  const long cb = bz * strC;
#pragma unroll
  for (int m = 0; m < 8; ++m) {
    const int rb = wr * 128 + m * 16 + (lane >> 4) * 4;
    float rs[4] = {0.f, 0.f, 0.f, 0.f};
#pragma unroll
    for (int n = 0; n < 4; ++n) {
      const int c = bcol + wc * 64 + n * 16 + lr;
      const float bv = (MODE == 0 || MODE == 1) ? (bias ? bias[c] : 0.0f) : 0.0f;
#pragma unroll
      for (int r = 0; r < 4; ++r) {
        const int row = brow + rb + r;
        float val = (acc[m][n][r] + bv) * scale;
        if (MODE == 0) {
          Cf[cb + (long)row * ldc + c] = val;
        } else if (MODE == 1) {
          Cb[cb + (long)row * ldc + c] = f2bf(val);
        } else if (MODE == 2) {
          const float e = __expf(val);
          rs[r] += e;
          Cb[cb + (long)row * ldc + c] = f2bf(e);
        } else {  // MODE 3
          Cb[cb + (long)row * ldc + c] = f2bf(val * ro[rb + r]);
        }
      }
    }
    if (MODE == 2) {
#pragma unroll
      for (int r = 0; r < 4; ++r) {
        float s = rs[r];
        s += __shfl_xor(s, 1, 64);
        s += __shfl_xor(s, 2, 64);
        s += __shfl_xor(s, 4, 64);
        s += __shfl_xor(s, 8, 64);
        if (lr == 0)
          part[(bz * 2048 + brow + rb + r) * 64 + bx * 4 + wc] = s;
      }
    }
  }
}

// Fused QKV projection: grid (8,32,3); z=0: Q->bf16 qb (scaled); z=1: K->fp32
// kc + bf16 kb (cache rows PAST..); z=2: V->fp32 vc + bf16 TRANSPOSED vtb.
__global__ __launch_bounds__(512, 2) void gemm_qkv(
    const u16* __restrict__ A, const u16* __restrict__ wq,
    const u16* __restrict__ wk, const u16* __restrict__ wv,
    const float* __restrict__ bq, const float* __restrict__ bk,
    const float* __restrict__ bv_, u16* __restrict__ qb,
    float* __restrict__ kc, u16* __restrict__ kbm,
    float* __restrict__ vc, u16* __restrict__ vtb, float qscale) {
  __shared__ __align__(16) u16 shA[2][256 * 64];
  __shared__ __align__(16) u16 shB[2][256 * 64];
  const int t = threadIdx.x;
  const int lane = t & 63;
  const int w = t >> 6;
  const int wr = w >> 2, wc = w & 3;
  const int lr = lane & 15, kb0 = (lane >> 4) * 16;

  const int gx = gridDim.x, gy = gridDim.y;
  const int nwg = gx * gy * gridDim.z;
  const int orig = blockIdx.x + gx * (blockIdx.y + gy * blockIdx.z);
  const int swz = (orig & 7) * (nwg >> 3) + (orig >> 3);
  const int bx = swz % gx;
  const int r1 = swz / gx;
  const int by = r1 % gy;
  const int bz = r1 / gy;  // 0=Q 1=K 2=V (block-uniform)
  const int brow = by * 256, bcol = bx * 256;

  const u16* Bw = (bz == 0) ? wq : (bz == 1) ? wk : wv;
  const float* bias = (bz == 0) ? bq : (bz == 1) ? bk : bv_;
  const u16* Ab = A + (long)brow * 2048;
  const u16* Bb = Bw + (long)bcol * 2048;
  const int NT = 2048 >> 6;

  f32x4 acc[8][4] = {};
  bf16x8 a[4][2], b0[2][2], b1[2][2];

  GEMM_MAIN_LOOP(Ab, Bb, 2048, 2048)

  if (bz == 0) {  // Q: bf16, scaled
#pragma unroll
    for (int m = 0; m < 8; ++m) {
      const int r0 = wr * 128 + m * 16 + (lane >> 4) * 4;
#pragma unroll
      for (int n = 0; n < 4; ++n) {
        const int c = bcol + wc * 64 + n * 16 + lr;
        const float bvv = bias[c];
#pragma unroll
        for (int r = 0; r < 4; ++r) {
          const int row = brow + r0 + r;
          qb[(long)row * 2048 + c] = f2bf((acc[m][n][r] + bvv) * qscale);
        }
      }
    }
  } else if (bz == 1) {  // K: fp32 kc + bf16 kb, remapped rows
#pragma unroll
    for (int m = 0; m < 8; ++m) {
      const int r0 = wr * 128 + m * 16 + (lane >> 4) * 4;
#pragma unroll
      for (int n = 0; n < 4; ++n) {
        const int c = bcol + wc * 64 + n * 16 + lr;
        const float bvv = bias[c];
#pragma unroll
        for (int r = 0; r < 4; ++r) {
          const int row = brow + r0 + r;
          const long orow = (long)((row >> 11) * CS + PAST_N + (row & (SEQ - 1)));
          const float val = acc[m][n][r] + bvv;
          kc[orow * 2048 + c] = val;
          kbm[orow * 2048 + c] = f2bf(val);
        }
      }
    }
  } else {  // V: fp32 vc (remapped) + bf16 transposed vtb[b][d][PAST+s]
#pragma unroll
    for (int m = 0; m < 8; ++m) {
      const int r0 = wr * 128 + m * 16 + (lane >> 4) * 4;
#pragma unroll
      for (int n = 0; n < 4; ++n) {
        const int c = bcol + wc * 64 + n * 16 + lr;
        const float bvv = bias[c];
        ushort4 pk4;
        const int row0 = brow + r0;
        const int bat = row0 >> 11;
        const long orow0 = (long)(bat * CS + PAST_N + (row0 & (SEQ - 1)));
#pragma unroll
        for (int r = 0; r < 4; ++r) {
          const float val = acc[m][n][r] + bvv;
          vc[(orow0 + r) * 2048 + c] = val;
          ((u16*)&pk4)[r] = f2bf(val);
        }
        *(ushort4*)(vtb + (long)bat * DM * CS + (long)c * CS + PAST_N +
                    (row0 & (SEQ - 1))) = pk4;
      }
    }
  }
}

// Merged fp32->bf16 casts: grid (4096,1,8). z 0-3: x slice z; z 4-7: Wq/Wk/Wv/Wo.
__global__ __launch_bounds__(256) void cast_all(
    const float* __restrict__ x, u16* __restrict__ xb,
    const float* __restrict__ wq, u16* __restrict__ wqb,
    const float* __restrict__ wk, u16* __restrict__ wkb,
    const float* __restrict__ wv, u16* __restrict__ wvb,
    const float* __restrict__ wo, u16* __restrict__ wob) {
  const int z = blockIdx.z;
  const float* src;
  u16* dst;
  if (z < 4) { src = x + (long)z * 4194304; dst = xb + (long)z * 4194304; }
  else if (z == 4) { src = wq; dst = wqb; }
  else if (z == 5) { src = wk; dst = wkb; }
  else if (z == 6) { src = wv; dst = wvb; }
  else { src = wo; dst = wob; }
  const int i = blockIdx.x * 256 + threadIdx.x;
  const float4 v = ((const float4*)src)[i];
  ushort4 o;
  o.x = f2bf(v.x); o.y = f2bf(v.y); o.z = f2bf(v.z); o.w = f2bf(v.w);
  ((ushort4*)dst)[i] = o;
}

// Fused past-KV pass: grid (64,64,8). z 0-3: pv batch z -> vc fp32 + vtb bf16
// transposed (single pv read). z 4-7: pk batch z-4 -> kc fp32 + kb bf16.
__global__ __launch_bounds__(256) void past_pass(
    const float* __restrict__ pk, const float* __restrict__ pv,
    float* __restrict__ kc, u16* __restrict__ kb,
    float* __restrict__ vc, u16* __restrict__ vtb) {
  const int z = blockIdx.z;
  const int t = threadIdx.x;
  if (z >= 4) {  // pk copy path: batch z-4
    const int bb = z - 4;
    const int i = (blockIdx.y * 64 + blockIdx.x) * 256 + t;
    const int d4 = DM / 4;
    const int p = i / d4, col = i - p * d4;
    const float4 v = ((const float4*)(pk + (long)bb * PAST_N * DM))[i];
    const long o = ((long)(bb * CS + p)) * d4 + col;
    ((float4*)kc)[o] = v;
    ushort4 u;
    u.x = f2bf(v.x); u.y = f2bf(v.y); u.z = f2bf(v.z); u.w = f2bf(v.w);
    ((ushort4*)kb)[o] = u;
    return;
  }
  // pv path: batch z; 32x32 tile at (k0, d0); read once, write vc + vtb^T
  __shared__ float tile[32][33];
  const int bb = z;
  const int k0 = blockIdx.x * 32, d0 = blockIdx.y * 32;
  const int k = t >> 3, q = t & 7;
  const float* src = pv + (long)bb * PAST_N * DM;
  const float4 v = *(const float4*)(src + (long)(k0 + k) * DM + d0 + q * 4);
  *(float4*)(vc + ((long)(bb * CS + k0 + k)) * DM + d0 + q * 4) = v;
  tile[k][q * 4 + 0] = v.x;
  tile[k][q * 4 + 1] = v.y;
  tile[k][q * 4 + 2] = v.z;
  tile[k][q * 4 + 3] = v.w;
  __syncthreads();
  const int d = t >> 3, q2 = t & 7;
  ushort4 o;
  ((u16*)&o)[0] = f2bf(tile[q2 * 4 + 0][d]);
  ((u16*)&o)[1] = f2bf(tile[q2 * 4 + 1][d]);
  ((u16*)&o)[2] = f2bf(tile[q2 * 4 + 2][d]);
  ((u16*)&o)[3] = f2bf(tile[q2 * 4 + 3][d]);
  *(ushort4*)(vtb + (long)bb * DM * CS + (long)(d0 + d) * CS + k0 + q2 * 4) = o;
}

extern "C" void kernel_launch(void* const* d_in, const int* in_sizes, int n_in,
                              void* d_out, int out_size, void* d_ws, size_t ws_size,
                              hipStream_t stream) {
  const float* x  = (const float*)d_in[0];
  const float* pk = (const float*)d_in[1];
  const float* pv = (const float*)d_in[2];
  const float* Wq = (const float*)d_in[3];
  const float* bq = (const float*)d_in[4];
  const float* Wk = (const float*)d_in[5];
  const float* bk = (const float*)d_in[6];
  const float* Wv = (const float*)d_in[7];
  const float* bv = (const float*)d_in[8];
  const float* Wo = (const float*)d_in[9];
  const float* bo = (const float*)d_in[10];

  float* out = (float*)d_out;
  float* kc = out + (long)NB * SEQ * DM;   // k_cache [4][4096][2048] fp32
  float* vc = kc + (long)NB * CS * DM;     // v_cache

  u16* ws = (u16*)d_ws;
  u16* xb  = ws;              // x bf16 [8192][2048]; reused as attn bf16 later
  u16* wqb = ws + 16777216;
  u16* wkb = wqb + 4194304;
  u16* wvb = wkb + 4194304;
  u16* wob = wvb + 4194304;
  u16* qb  = ws + 33554432;   // q bf16 (scaled) [8192][2048]
  u16* kb  = ws + 50331648;   // k_cache bf16 [4][4096][2048]
  u16* vtb = ws + 83886080;   // v_cache^T bf16 [4][2048][4096]
  u16* sc  = ws + 117440512;  // scores e-values bf16 [4][2048][4096]
  // partial row sums [4][2048][64] fp32 = 2MB, reuses dead wqb region
  float* part = (float*)wqb;

  const float qscale = 0.022097086912079608f;  // 1/sqrt(2048)

  cast_all<<<dim3(4096, 1, 8), 256, 0, stream>>>(
      x, xb, Wq, wqb, Wk, wkb, Wv, wvb, Wo, wob);

  // fused past-KV pass (single read of pk and pv each)
  past_pass<<<dim3(64, 64, 8), 256, 0, stream>>>(pk, pv, kc, kb, vc, vtb);

  // fused Q/K/V projections (one launch, 768 blocks)
  gemm_qkv<<<dim3(8, 32, 3), 512, 0, stream>>>(
      xb, wqb, wkb, wvb, bq, bk, bv, qb, kc, kb, vc, vtb, qscale);

  // scores: e = exp(q.k^T) -> bf16 sc + per-row partial sums (part)
  gemm256<2><<<dim3(16, 8, 4), 512, 0, stream>>>(
      qb, kb, nullptr, sc, nullptr, part, 2048, 2048, 2048, 4096,
      2048L * 2048, 4096L * 2048, 2048L * 4096, 1.0f);

  // attn = (e . vT) / rowsum -> bf16 into xb
  gemm256<3><<<dim3(8, 8, 4), 512, 0, stream>>>(
      sc, vtb, nullptr, xb, nullptr, part, 4096, 4096, 4096, 2048,
      2048L * 4096, 2048L * 4096, 2048L * 2048, 1.0f);

  // out = attn Wo^T + bo -> fp32
  gemm256<0><<<dim3(8, 32, 1), 512, 0, stream>>>(
      xb, wob, out, nullptr, bo, nullptr, 2048, 2048, 2048, 2048, 0, 0, 0, 1.0f);
}

// Round 14
// 726.702 us; speedup vs baseline: 1.0953x; 1.0953x over previous
//
#include <hip/hip_runtime.h>
#include <math.h>

typedef unsigned short u16;
typedef __bf16 bf16x8 __attribute__((ext_vector_type(8)));
typedef float f32x4 __attribute__((ext_vector_type(4)));
typedef short s16x8 __attribute__((ext_vector_type(8)));

#define DM 2048
#define NB 4
#define SEQ 2048
#define PAST_N 2048
#define CS 4096

__device__ __forceinline__ u16 f2bf(float f) {
  unsigned u = __float_as_uint(f);
  u += 0x7fff + ((u >> 16) & 1);
  return (u16)(u >> 16);
}
__device__ __forceinline__ float bf2f(u16 h) {
  return __uint_as_float(((unsigned)h) << 16);
}

__device__ __forceinline__ void gl_lds16(const u16* g, u16* l) {
  __builtin_amdgcn_global_load_lds(
      (const __attribute__((address_space(1))) unsigned*)g,
      (__attribute__((address_space(3))) unsigned*)l, 16, 0, 0);
}

// Swizzled LDS fragment read: tile row-major [256 rows][64 k] bf16 (128B/row),
// 16B slots XOR'd by row&7 (r2-verified structure).
__device__ __forceinline__ bf16x8 ldsfrag(const u16* s, int row, int colb) {
  const int byte_off = (row * 128 + colb) ^ ((row & 7) << 4);
  return *(const bf16x8*)((const char*)s + byte_off);
}

// Stage one 256x64 bf16 tile (32KB) with 512 threads: 4 x global_load_lds(16B).
// LDS dest linear (HW); SOURCE column pre-swizzled (rule #21).
__device__ __forceinline__ void stage4(const u16* __restrict__ g, int ld,
                                       u16* lwb, int t) {
#pragma unroll
  for (int j = 0; j < 4; ++j) {
    const int c = j * 512 + t;
    const int row = c >> 3;
    const int slot = (c & 7) ^ (row & 7);
    gl_lds16(g + (long)row * ld + slot * 8, lwb + j * 4096);
  }
}

#define LOADA(mh)                                                       \
  _Pragma("unroll") for (int mi = 0; mi < 4; ++mi) {                    \
    const int rwa = wr * 128 + ((mh) * 4 + mi) * 16 + lr;               \
    a[mi][0] = ldsfrag(sA, rwa, kb0);                                   \
    a[mi][1] = ldsfrag(sA, rwa, 64 + kb0);                              \
  }

#define LOADB(nh)                                                       \
  _Pragma("unroll") for (int ni = 0; ni < 2; ++ni) {                    \
    const int rwb = wc * 64 + ((nh) * 2 + ni) * 16 + lr;                \
    b[ni][0] = ldsfrag(sB, rwb, kb0);                                   \
    b[ni][1] = ldsfrag(sB, rwb, 64 + kb0);                              \
  }

#define MM(mh, nh)                                                      \
  _Pragma("unroll") for (int kk = 0; kk < 2; ++kk)                      \
  _Pragma("unroll") for (int mi = 0; mi < 4; ++mi)                      \
  _Pragma("unroll") for (int ni = 0; ni < 2; ++ni)                      \
    acc[(mh) * 4 + mi][(nh) * 2 + ni] =                                 \
        __builtin_amdgcn_mfma_f32_16x16x32_bf16(                        \
            a[mi][kk], b[ni][kk], acc[(mh) * 4 + mi][(nh) * 2 + ni],    \
            0, 0, 0);

#define PHASE_SYNC                                                      \
  __builtin_amdgcn_s_barrier();                                         \
  asm volatile("s_waitcnt lgkmcnt(0)" ::: "memory");                    \
  __builtin_amdgcn_sched_barrier(0);

// r2's 4-phase K-loop body, shared by the GEMM kernels via macro.
#define GEMM_MAIN_LOOP(Abp, Bbp, ldav, ldbv)                            \
  stage4(Abp, ldav, &shA[0][w * 512], t);                               \
  stage4(Bbp, ldbv, &shB[0][w * 512], t);                               \
  asm volatile("s_waitcnt vmcnt(0)" ::: "memory");                      \
  __builtin_amdgcn_s_barrier();                                         \
  for (int tt = 0; tt < NT; ++tt) {                                     \
    const int cur = tt & 1;                                             \
    const u16* sA = shA[cur];                                           \
    const u16* sB = shB[cur];                                           \
    const bool pf = (tt + 1 < NT);                                      \
    const int ko = (tt + 1) << 6;                                       \
    LOADA(0)                                                            \
    LOADB(0)                                                            \
    if (pf) stage4(Abp + ko, ldav, &shA[cur ^ 1][w * 512], t);          \
    PHASE_SYNC                                                          \
    __builtin_amdgcn_s_setprio(1);                                      \
    MM(0, 0)                                                            \
    __builtin_amdgcn_s_setprio(0);                                      \
    __builtin_amdgcn_s_barrier();                                       \
    LOADB(1)                                                            \
    if (pf) stage4(Bbp + ko, ldbv, &shB[cur ^ 1][w * 512], t);          \
    PHASE_SYNC                                                          \
    __builtin_amdgcn_s_setprio(1);                                      \
    MM(0, 1)                                                            \
    __builtin_amdgcn_s_setprio(0);                                      \
    __builtin_amdgcn_s_barrier();                                       \
    LOADA(1)                                                            \
    PHASE_SYNC                                                          \
    __builtin_amdgcn_s_setprio(1);                                      \
    MM(1, 1)                                                            \
    __builtin_amdgcn_s_setprio(0);                                      \
    __builtin_amdgcn_s_barrier();                                       \
    LOADB(0)                                                            \
    PHASE_SYNC                                                          \
    __builtin_amdgcn_s_setprio(1);                                      \
    MM(1, 0)                                                            \
    __builtin_amdgcn_s_setprio(0);                                      \
    if (pf) asm volatile("s_waitcnt vmcnt(0)" ::: "memory");            \
    __builtin_amdgcn_s_barrier();                                       \
  }

// C[M,N] = A[M,K] * B[N,K]^T (r2 core).
// MODE 0: fp32 out (+bias). MODE 1: bf16 out (+bias, *scale).
// MODE 2: scores — write bf16 exp(val); per-row partial sums (this wave's
//         64-col slice) -> part[bz][row][bx*4+wc] fp32.
// MODE 3: PV — preload rowsum partials (64/row), epilogue multiplies 1/sum.
template <int MODE>
__global__ __launch_bounds__(512, 2) void gemm256(
    const u16* __restrict__ A, const u16* __restrict__ B,
    float* __restrict__ Cf, u16* __restrict__ Cb, const float* __restrict__ bias,
    float* __restrict__ part,
    int K, int lda, int ldb, int ldc, long strA, long strB, long strC,
    float scale) {
  __shared__ __align__(16) u16 shA[2][256 * 64];
  __shared__ __align__(16) u16 shB[2][256 * 64];
  __shared__ float ro[256];
  const int t = threadIdx.x;
  const int lane = t & 63;
  const int w = t >> 6;
  const int wr = w >> 2, wc = w & 3;
  const int lr = lane & 15, kb0 = (lane >> 4) * 16;

  const int gx = gridDim.x, gy = gridDim.y;
  const int nwg = gx * gy * gridDim.z;
  const int orig = blockIdx.x + gx * (blockIdx.y + gy * blockIdx.z);
  const int swz = (orig & 7) * (nwg >> 3) + (orig >> 3);
  const int bx = swz % gx;
  const int r1 = swz / gx;
  const int by = r1 % gy;
  const long bz = r1 / gy;
  const int brow = by * 256, bcol = bx * 256;

  const u16* Ab = A + bz * strA + (long)brow * lda;
  const u16* Bb = B + bz * strB + (long)bcol * ldb;
  const int NT = K >> 6;

  if (MODE == 3) {
    // preload reciprocal row sums for this block's 256 rows
    if (t < 256) {
      const float* pr = part + (bz * 2048 + brow + t) * 64;
      float s = 0.f;
#pragma unroll 8
      for (int j = 0; j < 64; ++j) s += pr[j];
      ro[t] = 1.0f / s;
    }
    __syncthreads();
  }

  f32x4 acc[8][4] = {};
  bf16x8 a[4][2], b[2][2];

  GEMM_MAIN_LOOP(Ab, Bb, lda, ldb)

  const long cb = bz * strC;
#pragma unroll
  for (int m = 0; m < 8; ++m) {
    const int rb = wr * 128 + m * 16 + (lane >> 4) * 4;
    float rs[4] = {0.f, 0.f, 0.f, 0.f};
#pragma unroll
    for (int n = 0; n < 4; ++n) {
      const int c = bcol + wc * 64 + n * 16 + lr;
      const float bv = (MODE == 0 || MODE == 1) ? (bias ? bias[c] : 0.0f) : 0.0f;
#pragma unroll
      for (int r = 0; r < 4; ++r) {
        const int row = brow + rb + r;
        float val = (acc[m][n][r] + bv) * scale;
        if (MODE == 0) {
          Cf[cb + (long)row * ldc + c] = val;
        } else if (MODE == 1) {
          Cb[cb + (long)row * ldc + c] = f2bf(val);
        } else if (MODE == 2) {
          const float e = __expf(val);
          rs[r] += e;
          Cb[cb + (long)row * ldc + c] = f2bf(e);
        } else {  // MODE 3
          Cb[cb + (long)row * ldc + c] = f2bf(val * ro[rb + r]);
        }
      }
    }
    if (MODE == 2) {
      // reduce rs over the 16 lr-lanes (same rows, different cols)
#pragma unroll
      for (int r = 0; r < 4; ++r) {
        float s = rs[r];
        s += __shfl_xor(s, 1, 64);
        s += __shfl_xor(s, 2, 64);
        s += __shfl_xor(s, 4, 64);
        s += __shfl_xor(s, 8, 64);
        if (lr == 0)
          part[(bz * 2048 + brow + rb + r) * 64 + bx * 4 + wc] = s;
      }
    }
  }
}

// Fused QKV projection: grid (8,32,3); z=0: Q->bf16 qb (scaled); z=1: K->fp32
// kc + bf16 kb (cache rows PAST..); z=2: V->fp32 vc + bf16 TRANSPOSED vtb.
__global__ __launch_bounds__(512, 2) void gemm_qkv(
    const u16* __restrict__ A, const u16* __restrict__ wq,
    const u16* __restrict__ wk, const u16* __restrict__ wv,
    const float* __restrict__ bq, const float* __restrict__ bk,
    const float* __restrict__ bv_, u16* __restrict__ qb,
    float* __restrict__ kc, u16* __restrict__ kbm,
    float* __restrict__ vc, u16* __restrict__ vtb, float qscale) {
  __shared__ __align__(16) u16 shA[2][256 * 64];
  __shared__ __align__(16) u16 shB[2][256 * 64];
  const int t = threadIdx.x;
  const int lane = t & 63;
  const int w = t >> 6;
  const int wr = w >> 2, wc = w & 3;
  const int lr = lane & 15, kb0 = (lane >> 4) * 16;

  const int gx = gridDim.x, gy = gridDim.y;
  const int nwg = gx * gy * gridDim.z;
  const int orig = blockIdx.x + gx * (blockIdx.y + gy * blockIdx.z);
  const int swz = (orig & 7) * (nwg >> 3) + (orig >> 3);
  const int bx = swz % gx;
  const int r1 = swz / gx;
  const int by = r1 % gy;
  const int bz = r1 / gy;  // 0=Q 1=K 2=V (block-uniform)
  const int brow = by * 256, bcol = bx * 256;

  const u16* Bw = (bz == 0) ? wq : (bz == 1) ? wk : wv;
  const float* bias = (bz == 0) ? bq : (bz == 1) ? bk : bv_;
  const u16* Ab = A + (long)brow * 2048;
  const u16* Bb = Bw + (long)bcol * 2048;
  const int NT = 2048 >> 6;

  f32x4 acc[8][4] = {};
  bf16x8 a[4][2], b[2][2];

  GEMM_MAIN_LOOP(Ab, Bb, 2048, 2048)

  if (bz == 0) {  // Q: bf16, scaled
#pragma unroll
    for (int m = 0; m < 8; ++m) {
      const int r0 = wr * 128 + m * 16 + (lane >> 4) * 4;
#pragma unroll
      for (int n = 0; n < 4; ++n) {
        const int c = bcol + wc * 64 + n * 16 + lr;
        const float bvv = bias[c];
#pragma unroll
        for (int r = 0; r < 4; ++r) {
          const int row = brow + r0 + r;
          qb[(long)row * 2048 + c] = f2bf((acc[m][n][r] + bvv) * qscale);
        }
      }
    }
  } else if (bz == 1) {  // K: fp32 kc + bf16 kb, remapped rows
#pragma unroll
    for (int m = 0; m < 8; ++m) {
      const int r0 = wr * 128 + m * 16 + (lane >> 4) * 4;
#pragma unroll
      for (int n = 0; n < 4; ++n) {
        const int c = bcol + wc * 64 + n * 16 + lr;
        const float bvv = bias[c];
#pragma unroll
        for (int r = 0; r < 4; ++r) {
          const int row = brow + r0 + r;
          const long orow = (long)((row >> 11) * CS + PAST_N + (row & (SEQ - 1)));
          const float val = acc[m][n][r] + bvv;
          kc[orow * 2048 + c] = val;
          kbm[orow * 2048 + c] = f2bf(val);
        }
      }
    }
  } else {  // V: fp32 vc (remapped) + bf16 transposed vtb[b][d][PAST+s]
#pragma unroll
    for (int m = 0; m < 8; ++m) {
      const int r0 = wr * 128 + m * 16 + (lane >> 4) * 4;
#pragma unroll
      for (int n = 0; n < 4; ++n) {
        const int c = bcol + wc * 64 + n * 16 + lr;
        const float bvv = bias[c];
        ushort4 pk4;
        const int row0 = brow + r0;
        const int bat = row0 >> 11;
        const long orow0 = (long)(bat * CS + PAST_N + (row0 & (SEQ - 1)));
#pragma unroll
        for (int r = 0; r < 4; ++r) {
          const float val = acc[m][n][r] + bvv;
          vc[(orow0 + r) * 2048 + c] = val;
          ((u16*)&pk4)[r] = f2bf(val);
        }
        *(ushort4*)(vtb + (long)bat * DM * CS + (long)c * CS + PAST_N +
                    (row0 & (SEQ - 1))) = pk4;
      }
    }
  }
}

// Merged fp32->bf16 casts: grid (4096,1,8). z 0-3: x slice z; z 4-7: Wq/Wk/Wv/Wo.
__global__ __launch_bounds__(256) void cast_all(
    const float* __restrict__ x, u16* __restrict__ xb,
    const float* __restrict__ wq, u16* __restrict__ wqb,
    const float* __restrict__ wk, u16* __restrict__ wkb,
    const float* __restrict__ wv, u16* __restrict__ wvb,
    const float* __restrict__ wo, u16* __restrict__ wob) {
  const int z = blockIdx.z;
  const float* src;
  u16* dst;
  if (z < 4) { src = x + (long)z * 4194304; dst = xb + (long)z * 4194304; }
  else if (z == 4) { src = wq; dst = wqb; }
  else if (z == 5) { src = wk; dst = wkb; }
  else if (z == 6) { src = wv; dst = wvb; }
  else { src = wo; dst = wob; }
  const int i = blockIdx.x * 256 + threadIdx.x;
  const float4 v = ((const float4*)src)[i];
  ushort4 o;
  o.x = f2bf(v.x); o.y = f2bf(v.y); o.z = f2bf(v.z); o.w = f2bf(v.w);
  ((ushort4*)dst)[i] = o;
}

// Fused past-KV pass: grid (64,64,8). z 0-3: pv batch z -> vc fp32 + vtb bf16
// transposed (single pv read). z 4-7: pk batch z-4 -> kc fp32 + kb bf16.
__global__ __launch_bounds__(256) void past_pass(
    const float* __restrict__ pk, const float* __restrict__ pv,
    float* __restrict__ kc, u16* __restrict__ kb,
    float* __restrict__ vc, u16* __restrict__ vtb) {
  const int z = blockIdx.z;
  const int t = threadIdx.x;
  if (z >= 4) {  // pk copy path: batch z-4
    const int bb = z - 4;
    const int i = (blockIdx.y * 64 + blockIdx.x) * 256 + t;
    const int d4 = DM / 4;
    const int p = i / d4, col = i - p * d4;
    const float4 v = ((const float4*)(pk + (long)bb * PAST_N * DM))[i];
    const long o = ((long)(bb * CS + p)) * d4 + col;
    ((float4*)kc)[o] = v;
    ushort4 u;
    u.x = f2bf(v.x); u.y = f2bf(v.y); u.z = f2bf(v.z); u.w = f2bf(v.w);
    ((ushort4*)kb)[o] = u;
    return;
  }
  // pv path: batch z; 32x32 tile at (k0, d0); read once, write vc + vtb^T
  __shared__ float tile[32][33];
  const int bb = z;
  const int k0 = blockIdx.x * 32, d0 = blockIdx.y * 32;
  const int k = t >> 3, q = t & 7;
  const float* src = pv + (long)bb * PAST_N * DM;
  const float4 v = *(const float4*)(src + (long)(k0 + k) * DM + d0 + q * 4);
  *(float4*)(vc + ((long)(bb * CS + k0 + k)) * DM + d0 + q * 4) = v;
  tile[k][q * 4 + 0] = v.x;
  tile[k][q * 4 + 1] = v.y;
  tile[k][q * 4 + 2] = v.z;
  tile[k][q * 4 + 3] = v.w;
  __syncthreads();
  const int d = t >> 3, q2 = t & 7;
  ushort4 o;
  ((u16*)&o)[0] = f2bf(tile[q2 * 4 + 0][d]);
  ((u16*)&o)[1] = f2bf(tile[q2 * 4 + 1][d]);
  ((u16*)&o)[2] = f2bf(tile[q2 * 4 + 2][d]);
  ((u16*)&o)[3] = f2bf(tile[q2 * 4 + 3][d]);
  *(ushort4*)(vtb + (long)bb * DM * CS + (long)(d0 + d) * CS + k0 + q2 * 4) = o;
}

extern "C" void kernel_launch(void* const* d_in, const int* in_sizes, int n_in,
                              void* d_out, int out_size, void* d_ws, size_t ws_size,
                              hipStream_t stream) {
  const float* x  = (const float*)d_in[0];
  const float* pk = (const float*)d_in[1];
  const float* pv = (const float*)d_in[2];
  const float* Wq = (const float*)d_in[3];
  const float* bq = (const float*)d_in[4];
  const float* Wk = (const float*)d_in[5];
  const float* bk = (const float*)d_in[6];
  const float* Wv = (const float*)d_in[7];
  const float* bv = (const float*)d_in[8];
  const float* Wo = (const float*)d_in[9];
  const float* bo = (const float*)d_in[10];

  float* out = (float*)d_out;
  float* kc = out + (long)NB * SEQ * DM;   // k_cache [4][4096][2048] fp32
  float* vc = kc + (long)NB * CS * DM;     // v_cache

  u16* ws = (u16*)d_ws;
  u16* xb  = ws;              // x bf16 [8192][2048]; reused as attn bf16 later
  u16* wqb = ws + 16777216;
  u16* wkb = wqb + 4194304;
  u16* wvb = wkb + 4194304;
  u16* wob = wvb + 4194304;
  u16* qb  = ws + 33554432;   // q bf16 (scaled) [8192][2048]
  u16* kb  = ws + 50331648;   // k_cache bf16 [4][4096][2048]
  u16* vtb = ws + 83886080;   // v_cache^T bf16 [4][2048][4096]
  u16* sc  = ws + 117440512;  // scores e-values bf16 [4][2048][4096]
  // partial row sums [4][2048][64] fp32 = 2MB, reuses dead wqb region
  float* part = (float*)wqb;

  const float qscale = 0.022097086912079608f;  // 1/sqrt(2048)

  cast_all<<<dim3(4096, 1, 8), 256, 0, stream>>>(
      x, xb, Wq, wqb, Wk, wkb, Wv, wvb, Wo, wob);

  // fused past-KV pass (single read of pk and pv each)
  past_pass<<<dim3(64, 64, 8), 256, 0, stream>>>(pk, pv, kc, kb, vc, vtb);

  // fused Q/K/V projections (one launch, 768 blocks)
  gemm_qkv<<<dim3(8, 32, 3), 512, 0, stream>>>(
      xb, wqb, wkb, wvb, bq, bk, bv, qb, kc, kb, vc, vtb, qscale);

  // scores: e = exp(q.k^T) -> bf16 sc + per-row partial sums (part)
  gemm256<2><<<dim3(16, 8, 4), 512, 0, stream>>>(
      qb, kb, nullptr, sc, nullptr, part, 2048, 2048, 2048, 4096,
      2048L * 2048, 4096L * 2048, 2048L * 4096, 1.0f);

  // attn = (e . vT) / rowsum -> bf16 into xb
  gemm256<3><<<dim3(8, 8, 4), 512, 0, stream>>>(
      sc, vtb, nullptr, xb, nullptr, part, 4096, 4096, 4096, 2048,
      2048L * 4096, 2048L * 4096, 2048L * 2048, 1.0f);

  // out = attn Wo^T + bo -> fp32
  gemm256<0><<<dim3(8, 32, 1), 512, 0, stream>>>(
      xb, wob, out, nullptr, bo, nullptr, 2048, 2048, 2048, 2048, 0, 0, 0, 1.0f);
}